// Round 12
// baseline (136.946 us; speedup 1.0000x reference)
//
#include <hip/hip_runtime.h>
#include <hip/hip_bf16.h>

#define CCH 256

typedef float f4 __attribute__((ext_vector_type(4)));

// ---------------- Kernel 1: merged pool (ALL loads temporal this round) ----------------
// wave-per-row: 64 lanes x 16 f4 = 4096 floats, 16-deep burst, (256,2) bounds.
// R11 postmortem: NT loads on rgb/dep ran at 2.1 TB/s HBM; testing the
// hypothesis that the nontemporal (no-allocate) load path is throughput-capped.
// rw: 0..8191 rgb -> nodes row 2; 8192..16383 dep -> row 3; 16384..24575 x_ful -> row 1.
__global__ __launch_bounds__(256, 2) void pool_kernel(
    const float* __restrict__ rgb, const float* __restrict__ dep,
    const float* __restrict__ xf, float* __restrict__ nodes /* [32][4][256] */)
{
    const int rw   = blockIdx.x * 4 + (threadIdx.x >> 6);  // 0..24575
    const int lane = threadIdx.x & 63;
    const int tensor = rw >> 13;              // 0 rgb, 1 dep, 2 x_ful
    const int row    = rw & 8191;             // b*256 + c
    const float* base = (tensor == 0) ? rgb : (tensor == 1) ? dep : xf;
    const f4* src = (const f4*)(base + (size_t)row * 4096);

    f4 v[16];
#pragma unroll
    for (int j = 0; j < 16; ++j) v[j] = src[lane + 64 * j];
    f4 a0 = v[0] + v[1], a1 = v[2] + v[3], a2 = v[4] + v[5], a3 = v[6] + v[7];
    f4 a4 = v[8] + v[9], a5 = v[10] + v[11], a6 = v[12] + v[13], a7 = v[14] + v[15];
    f4 acc = ((a0 + a1) + (a2 + a3)) + ((a4 + a5) + (a6 + a7));

    float s = acc.x + acc.y + acc.z + acc.w;
#pragma unroll
    for (int off = 32; off; off >>= 1) s += __shfl_down(s, off, 64);
    if (lane == 0) {
        const int b = row >> 8, c = row & 255;
        const int nrow = (tensor == 2) ? 1 : (2 + tensor);
        nodes[(size_t)b * 1024 + nrow * CCH + c] = s * (1.f / 4096.f);
    }
}

// ---------------- Kernel 2a: layer-0 per-(batch,head) GAT, K split across 4 groups ----------------
__global__ __launch_bounds__(1024) void gatL0_kernel(
    const float* __restrict__ nodes, const float* __restrict__ tok,
    const float* __restrict__ W0, const float* __restrict__ as0,
    const float* __restrict__ ad0, float* __restrict__ msg1)
{
    const int bid = blockIdx.x, b = bid >> 2, h = bid & 3;
    const int t = threadIdx.x, c = t & 255, kq = t >> 8;
    const int lane = t & 63, wv = t >> 6;       // wv 0..15

    __shared__ float X[4][CCH];
    __shared__ float xpart[3][4][CCH];          // kq=1..3 partials (12 KB)
    __shared__ float redl[4][8];
    __shared__ float esed[8];
    __shared__ float alpha[4][4];

    X[kq][c] = (kq == 0) ? tok[c] : nodes[(size_t)b * 1024 + kq * 256 + c];
    __syncthreads();

    float acc[4] = {0.f, 0.f, 0.f, 0.f};
    const float* Wp = W0 + h * 256 + c;
    const int kb0 = kq * 64;
    for (int kb = 0; kb < 64; kb += 16) {
        float wr[16];
#pragma unroll
        for (int u = 0; u < 16; ++u) wr[u] = Wp[(size_t)(kb0 + kb + u) * 1024];
#pragma unroll
        for (int u = 0; u < 16; ++u) {
            const int k = kb0 + kb + u;
            float w = wr[u];
            acc[0] += X[0][k] * w;
            acc[1] += X[1][k] * w;
            acc[2] += X[2][k] * w;
            acc[3] += X[3][k] * w;
        }
    }
    if (kq) {
#pragma unroll
        for (int n = 0; n < 4; ++n) xpart[kq - 1][n][c] = acc[n];
    }
    __syncthreads();

    if (kq == 0) {
#pragma unroll
        for (int n = 0; n < 4; ++n)
            acc[n] += xpart[0][n][c] + xpart[1][n][c] + xpart[2][n][c];

        const float av = as0[h * 256 + c], dv = ad0[h * 256 + c];
        float rv[8];
#pragma unroll
        for (int n = 0; n < 4; ++n) { rv[n] = acc[n] * av; rv[4 + n] = acc[n] * dv; }
#pragma unroll
        for (int i = 0; i < 8; ++i)
#pragma unroll
            for (int off = 32; off; off >>= 1)
                rv[i] += __shfl_down(rv[i], off, 64);
        if (lane == 0) {
#pragma unroll
            for (int i = 0; i < 8; ++i) redl[wv][i] = rv[i];
        }
    }
    __syncthreads();
    if (t < 8) esed[t] = redl[0][t] + redl[1][t] + redl[2][t] + redl[3][t];
    __syncthreads();

    if (t < 4) {
        const int cnt[4]     = {4, 3, 3, 3};
        const int srcs[4][4] = {{1,2,3,0},{2,3,1,0},{1,3,2,0},{1,2,3,0}};
        const int d = t, n = cnt[d];
        float v[4], m = -1e30f;
        for (int s = 0; s < n; ++s) {
            float e = esed[srcs[d][s]] + esed[4 + d];
            e = (e >= 0.f) ? e : 0.2f * e;           // leaky_relu 0.2
            v[s] = e; m = fmaxf(m, e);
        }
        float den = 0.f;
        for (int s = 0; s < n; ++s) { v[s] = __expf(v[s] - m); den += v[s]; }
        float inv = 1.f / den;
        for (int s = 0; s < n; ++s) alpha[d][s] = v[s] * inv;
        for (int s = n; s < 4; ++s) alpha[d][s] = 0.f;
    }
    __syncthreads();

    if (kq == 0) {
        const int srcs2[4][4] = {{1,2,3,0},{2,3,1,0},{1,3,2,0},{1,2,3,0}};
#pragma unroll
        for (int d = 0; d < 4; ++d) {
            float s = 0.f;
#pragma unroll
            for (int sl = 0; sl < 4; ++sl)
                s += alpha[d][sl] * acc[srcs2[d][sl]];
            msg1[(size_t)b * 4096 + h * 1024 + d * 256 + c] = s;
        }
    }
}

// ---------------- Kernel 2b: recompute gl1 + layer-1 GAT (token dst only) ----------------
__global__ __launch_bounds__(1024) void gatL1_kernel(
    const float* __restrict__ nodes, const float* __restrict__ tok,
    const float* __restrict__ msg1,
    const float* __restrict__ b0, const float* __restrict__ g0,
    const float* __restrict__ be0,
    const float* __restrict__ W1, const float* __restrict__ as1,
    const float* __restrict__ ad1, float* __restrict__ msg2tok)
{
    const int bid = blockIdx.x, b = bid >> 2, h = bid & 3;
    const int t = threadIdx.x, c = t & 255, kq = t >> 8;   // kq doubles as node d
    const int lane = t & 63, wv = t >> 6;

    __shared__ float X[4][CCH];                 // gl1
    __shared__ float xpart[3][4][CCH];
    __shared__ float redln[16][2];
    __shared__ float mu_s[4], rstd_s[4];
    __shared__ float redl[4][8];
    __shared__ float esed[8];
    __shared__ float alpha[4][4];

    {
        const float* m1 = msg1 + (size_t)b * 4096 + kq * 256 + c;  // h stride 1024
        float s = m1[0] + m1[1024] + m1[2048] + m1[3072];
        float x0 = (kq == 0) ? tok[c] : nodes[(size_t)b * 1024 + kq * 256 + c];
        float gv = 0.25f * s + b0[c] + x0;
        float ss = gv, qq = gv * gv;
#pragma unroll
        for (int off = 32; off; off >>= 1) {
            ss += __shfl_down(ss, off, 64);
            qq += __shfl_down(qq, off, 64);
        }
        if (lane == 0) { redln[wv][0] = ss; redln[wv][1] = qq; }
        __syncthreads();
        if (t < 4) {
            float s4 = redln[4*t][0] + redln[4*t+1][0] + redln[4*t+2][0] + redln[4*t+3][0];
            float q4 = redln[4*t][1] + redln[4*t+1][1] + redln[4*t+2][1] + redln[4*t+3][1];
            float mu  = s4 * (1.f / 256.f);
            float var = q4 * (1.f / 256.f) - mu * mu;
            mu_s[t] = mu; rstd_s[t] = rsqrtf(var + 1e-5f);
        }
        __syncthreads();
        X[kq][c] = fmaxf((gv - mu_s[kq]) * rstd_s[kq] * g0[c] + be0[c], 0.f);
    }
    __syncthreads();

    float acc[4] = {0.f, 0.f, 0.f, 0.f};
    const float* Wp = W1 + h * 256 + c;
    const int kb0 = kq * 64;
    for (int kb = 0; kb < 64; kb += 16) {
        float wr[16];
#pragma unroll
        for (int u = 0; u < 16; ++u) wr[u] = Wp[(size_t)(kb0 + kb + u) * 1024];
#pragma unroll
        for (int u = 0; u < 16; ++u) {
            const int k = kb0 + kb + u;
            float w = wr[u];
            acc[0] += X[0][k] * w;
            acc[1] += X[1][k] * w;
            acc[2] += X[2][k] * w;
            acc[3] += X[3][k] * w;
        }
    }
    if (kq) {
#pragma unroll
        for (int n = 0; n < 4; ++n) xpart[kq - 1][n][c] = acc[n];
    }
    __syncthreads();

    if (kq == 0) {
#pragma unroll
        for (int n = 0; n < 4; ++n)
            acc[n] += xpart[0][n][c] + xpart[1][n][c] + xpart[2][n][c];

        const float av = as1[h * 256 + c], dv = ad1[h * 256 + c];
        float rv[8];
#pragma unroll
        for (int n = 0; n < 4; ++n) { rv[n] = acc[n] * av; rv[4 + n] = acc[n] * dv; }
#pragma unroll
        for (int i = 0; i < 8; ++i)
#pragma unroll
            for (int off = 32; off; off >>= 1)
                rv[i] += __shfl_down(rv[i], off, 64);
        if (lane == 0) {
#pragma unroll
            for (int i = 0; i < 8; ++i) redl[wv][i] = rv[i];
        }
    }
    __syncthreads();
    if (t < 8) esed[t] = redl[0][t] + redl[1][t] + redl[2][t] + redl[3][t];
    __syncthreads();

    if (t == 0) {   // only dst 0 (token) needed downstream
        const int srcs0[4] = {1, 2, 3, 0};
        float v[4], m = -1e30f;
        for (int s = 0; s < 4; ++s) {
            float e = esed[srcs0[s]] + esed[4];
            e = (e >= 0.f) ? e : 0.2f * e;
            v[s] = e; m = fmaxf(m, e);
        }
        float den = 0.f;
        for (int s = 0; s < 4; ++s) { v[s] = __expf(v[s] - m); den += v[s]; }
        float inv = 1.f / den;
        for (int s = 0; s < 4; ++s) alpha[0][s] = v[s] * inv;
    }
    __syncthreads();

    if (kq == 0) {
        const int srcs0[4] = {1, 2, 3, 0};
        float s = 0.f;
#pragma unroll
        for (int sl = 0; sl < 4; ++sl)
            s += alpha[0][sl] * acc[srcs0[sl]];
        msg2tok[(size_t)b * 1024 + h * 256 + c] = s;
    }
}

// ---------------- Kernel 2c: finish — token-row LN chain -> scale ----------------
__global__ __launch_bounds__(256) void finish_kernel(
    const float* __restrict__ tok,
    const float* __restrict__ msg1, const float* __restrict__ msg2tok,
    const float* __restrict__ b0, const float* __restrict__ g0,
    const float* __restrict__ be0,
    const float* __restrict__ b1, const float* __restrict__ g1,
    const float* __restrict__ be1,
    float* __restrict__ scale)
{
    const int b = blockIdx.x, c = threadIdx.x;
    const int lane = c & 63, wv = c >> 6;
    __shared__ float redl[4][2];
    __shared__ float mrs[2];

    const float* m1 = msg1 + (size_t)b * 4096 + c;
    float gv1 = 0.25f * (m1[0] + m1[1024] + m1[2048] + m1[3072]) + b0[c] + tok[c];
    {
        float s = gv1, q = gv1 * gv1;
#pragma unroll
        for (int off = 32; off; off >>= 1) { s += __shfl_down(s, off, 64); q += __shfl_down(q, off, 64); }
        if (lane == 0) { redl[wv][0] = s; redl[wv][1] = q; }
        __syncthreads();
        if (c == 0) {
            float ss = redl[0][0] + redl[1][0] + redl[2][0] + redl[3][0];
            float qq = redl[0][1] + redl[1][1] + redl[2][1] + redl[3][1];
            float mu = ss * (1.f / 256.f);
            mrs[0] = mu; mrs[1] = rsqrtf(qq * (1.f / 256.f) - mu * mu + 1e-5f);
        }
        __syncthreads();
    }
    float y1 = fmaxf((gv1 - mrs[0]) * mrs[1] * g0[c] + be0[c], 0.f);
    __syncthreads();

    const float* m2 = msg2tok + (size_t)b * 1024 + c;
    float gv2 = 0.25f * (m2[0] + m2[256] + m2[512] + m2[768]) + b1[c] + y1;
    {
        float s = gv2, q = gv2 * gv2;
#pragma unroll
        for (int off = 32; off; off >>= 1) { s += __shfl_down(s, off, 64); q += __shfl_down(q, off, 64); }
        if (lane == 0) { redl[wv][0] = s; redl[wv][1] = q; }
        __syncthreads();
        if (c == 0) {
            float ss = redl[0][0] + redl[1][0] + redl[2][0] + redl[3][0];
            float qq = redl[0][1] + redl[1][1] + redl[2][1] + redl[3][1];
            float mu = ss * (1.f / 256.f);
            mrs[0] = mu; mrs[1] = rsqrtf(qq * (1.f / 256.f) - mu * mu + 1e-5f);
        }
        __syncthreads();
    }
    float y2 = fmaxf((gv2 - mrs[0]) * mrs[1] * g1[c] + be1[c], 0.f);
    scale[(size_t)b * CCH + c] = 1.f + 1.f / (1.f + __expf(-y2));
}

// ---------------- Kernel 3: out = x_ful * (1 + sigmoid), nontemporal store ----------------
__global__ __launch_bounds__(256) void apply_kernel(
    const float* __restrict__ xf, const float* __restrict__ scale,
    float* __restrict__ out, int total4)
{
    int idx = blockIdx.x * 256 + threadIdx.x;
    const int stride = gridDim.x * 256;
    const f4* in4 = (const f4*)xf;
    f4* out4 = (f4*)out;
    for (; idx < total4; idx += stride) {
        f4 v = in4[idx];
        const float s = scale[idx >> 10];          // 1024 float4 per (b,c) row
        f4 o = v * s;
        __builtin_nontemporal_store(o, out4 + idx);
    }
}

extern "C" void kernel_launch(void* const* d_in, const int* in_sizes, int n_in,
                              void* d_out, int out_size, void* d_ws, size_t ws_size,
                              hipStream_t stream) {
    const float* x_ful = (const float*)d_in[0];
    const float* rgb   = (const float*)d_in[1];
    const float* dep   = (const float*)d_in[2];
    const float* tok   = (const float*)d_in[3];
    const float* W0  = (const float*)d_in[4];
    const float* as0 = (const float*)d_in[5];
    const float* ad0 = (const float*)d_in[6];
    const float* b0  = (const float*)d_in[7];
    const float* g0  = (const float*)d_in[8];
    const float* be0 = (const float*)d_in[9];
    const float* W1  = (const float*)d_in[10];
    const float* as1 = (const float*)d_in[11];
    const float* ad1 = (const float*)d_in[12];
    const float* b1  = (const float*)d_in[13];
    const float* g1  = (const float*)d_in[14];
    const float* be1 = (const float*)d_in[15];

    float* ws      = (float*)d_ws;
    float* nodes   = ws;                 // [32][4][256]    = 32768 floats
    float* scale   = ws + 32768;         // [32][256]       =  8192 floats
    float* msg1    = ws + 40960;         // [32][4][4][256] = 131072 floats
    float* msg2tok = ws + 172032;        // [32][4][256]    = 32768 floats
    float* out     = (float*)d_out;

    pool_kernel<<<6144, 256, 0, stream>>>(rgb, dep, x_ful, nodes);
    gatL0_kernel<<<128, 1024, 0, stream>>>(nodes, tok, W0, as0, ad0, msg1);
    gatL1_kernel<<<128, 1024, 0, stream>>>(nodes, tok, msg1, b0, g0, be0,
                                           W1, as1, ad1, msg2tok);
    finish_kernel<<<32, 256, 0, stream>>>(tok, msg1, msg2tok,
                                          b0, g0, be0, b1, g1, be1, scale);
    const int total4 = 32 * CCH * 64 * 64 / 4;            // 8,388,608 float4
    apply_kernel<<<2048, 256, 0, stream>>>(x_ful, scale, out, total4);
}

// Round 13
// 132.958 us; speedup vs baseline: 1.0300x; 1.0300x over previous
//
#include <hip/hip_runtime.h>
#include <hip/hip_bf16.h>

#define CCH 256

typedef float f4 __attribute__((ext_vector_type(4)));

// ---------------- Kernel 1: pool, max-TLP form ----------------
// One 256-thread block per row (24576 blocks): each thread only 4 f4 loads ->
// latency hidden by wave count (TLP), not staging depth (which the compiler
// keeps re-rolling: VGPR=36 in R11/R12). NT on rgb/dep (R12 showed NT faster);
// temporal x_ful, dispatched last -> freshest in L3 for apply.
__global__ __launch_bounds__(256) void pool_kernel(
    const float* __restrict__ rgb, const float* __restrict__ dep,
    const float* __restrict__ xf, float* __restrict__ nodes /* [32][4][256] */)
{
    const int bid = blockIdx.x;               // 0..24575
    const int t = threadIdx.x;                // 0..255
    const int lane = t & 63, wv = t >> 6;
    const int tensor = bid >> 13;             // 0 rgb, 1 dep, 2 x_ful
    const int row    = bid & 8191;            // b*256 + c
    const float* base = (tensor == 0) ? rgb : (tensor == 1) ? dep : xf;
    const f4* src = (const f4*)(base + (size_t)row * 4096);

    f4 v0, v1, v2, v3;
    if (tensor < 2) {
        v0 = __builtin_nontemporal_load(src + t);
        v1 = __builtin_nontemporal_load(src + t + 256);
        v2 = __builtin_nontemporal_load(src + t + 512);
        v3 = __builtin_nontemporal_load(src + t + 768);
    } else {
        v0 = src[t]; v1 = src[t + 256]; v2 = src[t + 512]; v3 = src[t + 768];
    }
    f4 a = (v0 + v1) + (v2 + v3);
    float s = a.x + a.y + a.z + a.w;
#pragma unroll
    for (int off = 32; off; off >>= 1) s += __shfl_down(s, off, 64);

    __shared__ float red[4];
    if (lane == 0) red[wv] = s;
    __syncthreads();
    if (t == 0) {
        const int b = row >> 8, c = row & 255;
        const int nrow = (tensor == 2) ? 1 : (2 + tensor);
        nodes[(size_t)b * 1024 + nrow * CCH + c] =
            (red[0] + red[1] + red[2] + red[3]) * (1.f / 4096.f);
    }
}

// ---------------- Kernel 2a: layer-0 per-(batch,head) GAT, K split across 4 groups ----------------
__global__ __launch_bounds__(1024) void gatL0_kernel(
    const float* __restrict__ nodes, const float* __restrict__ tok,
    const float* __restrict__ W0, const float* __restrict__ as0,
    const float* __restrict__ ad0, float* __restrict__ msg1)
{
    const int bid = blockIdx.x, b = bid >> 2, h = bid & 3;
    const int t = threadIdx.x, c = t & 255, kq = t >> 8;
    const int lane = t & 63, wv = t >> 6;       // wv 0..15

    __shared__ float X[4][CCH];
    __shared__ float xpart[3][4][CCH];          // kq=1..3 partials (12 KB)
    __shared__ float redl[4][8];
    __shared__ float esed[8];
    __shared__ float alpha[4][4];

    X[kq][c] = (kq == 0) ? tok[c] : nodes[(size_t)b * 1024 + kq * 256 + c];
    __syncthreads();

    float acc[4] = {0.f, 0.f, 0.f, 0.f};
    const float* Wp = W0 + h * 256 + c;
    const int kb0 = kq * 64;
    for (int kb = 0; kb < 64; kb += 16) {
        float wr[16];
#pragma unroll
        for (int u = 0; u < 16; ++u) wr[u] = Wp[(size_t)(kb0 + kb + u) * 1024];
#pragma unroll
        for (int u = 0; u < 16; ++u) {
            const int k = kb0 + kb + u;
            float w = wr[u];
            acc[0] += X[0][k] * w;
            acc[1] += X[1][k] * w;
            acc[2] += X[2][k] * w;
            acc[3] += X[3][k] * w;
        }
    }
    if (kq) {
#pragma unroll
        for (int n = 0; n < 4; ++n) xpart[kq - 1][n][c] = acc[n];
    }
    __syncthreads();

    if (kq == 0) {
#pragma unroll
        for (int n = 0; n < 4; ++n)
            acc[n] += xpart[0][n][c] + xpart[1][n][c] + xpart[2][n][c];

        const float av = as0[h * 256 + c], dv = ad0[h * 256 + c];
        float rv[8];
#pragma unroll
        for (int n = 0; n < 4; ++n) { rv[n] = acc[n] * av; rv[4 + n] = acc[n] * dv; }
#pragma unroll
        for (int i = 0; i < 8; ++i)
#pragma unroll
            for (int off = 32; off; off >>= 1)
                rv[i] += __shfl_down(rv[i], off, 64);
        if (lane == 0) {
#pragma unroll
            for (int i = 0; i < 8; ++i) redl[wv][i] = rv[i];
        }
    }
    __syncthreads();
    if (t < 8) esed[t] = redl[0][t] + redl[1][t] + redl[2][t] + redl[3][t];
    __syncthreads();

    if (t < 4) {
        const int cnt[4]     = {4, 3, 3, 3};
        const int srcs[4][4] = {{1,2,3,0},{2,3,1,0},{1,3,2,0},{1,2,3,0}};
        const int d = t, n = cnt[d];
        float v[4], m = -1e30f;
        for (int s = 0; s < n; ++s) {
            float e = esed[srcs[d][s]] + esed[4 + d];
            e = (e >= 0.f) ? e : 0.2f * e;           // leaky_relu 0.2
            v[s] = e; m = fmaxf(m, e);
        }
        float den = 0.f;
        for (int s = 0; s < n; ++s) { v[s] = __expf(v[s] - m); den += v[s]; }
        float inv = 1.f / den;
        for (int s = 0; s < n; ++s) alpha[d][s] = v[s] * inv;
        for (int s = n; s < 4; ++s) alpha[d][s] = 0.f;
    }
    __syncthreads();

    if (kq == 0) {
        const int srcs2[4][4] = {{1,2,3,0},{2,3,1,0},{1,3,2,0},{1,2,3,0}};
#pragma unroll
        for (int d = 0; d < 4; ++d) {
            float s = 0.f;
#pragma unroll
            for (int sl = 0; sl < 4; ++sl)
                s += alpha[d][sl] * acc[srcs2[d][sl]];
            msg1[(size_t)b * 4096 + h * 1024 + d * 256 + c] = s;
        }
    }
}

// ---------------- Kernel 2b: recompute gl1 + layer-1 GAT (token dst only) ----------------
__global__ __launch_bounds__(1024) void gatL1_kernel(
    const float* __restrict__ nodes, const float* __restrict__ tok,
    const float* __restrict__ msg1,
    const float* __restrict__ b0, const float* __restrict__ g0,
    const float* __restrict__ be0,
    const float* __restrict__ W1, const float* __restrict__ as1,
    const float* __restrict__ ad1, float* __restrict__ msg2tok)
{
    const int bid = blockIdx.x, b = bid >> 2, h = bid & 3;
    const int t = threadIdx.x, c = t & 255, kq = t >> 8;   // kq doubles as node d
    const int lane = t & 63, wv = t >> 6;

    __shared__ float X[4][CCH];                 // gl1
    __shared__ float xpart[3][4][CCH];
    __shared__ float redln[16][2];
    __shared__ float mu_s[4], rstd_s[4];
    __shared__ float redl[4][8];
    __shared__ float esed[8];
    __shared__ float alpha[4][4];

    {
        const float* m1 = msg1 + (size_t)b * 4096 + kq * 256 + c;  // h stride 1024
        float s = m1[0] + m1[1024] + m1[2048] + m1[3072];
        float x0 = (kq == 0) ? tok[c] : nodes[(size_t)b * 1024 + kq * 256 + c];
        float gv = 0.25f * s + b0[c] + x0;
        float ss = gv, qq = gv * gv;
#pragma unroll
        for (int off = 32; off; off >>= 1) {
            ss += __shfl_down(ss, off, 64);
            qq += __shfl_down(qq, off, 64);
        }
        if (lane == 0) { redln[wv][0] = ss; redln[wv][1] = qq; }
        __syncthreads();
        if (t < 4) {
            float s4 = redln[4*t][0] + redln[4*t+1][0] + redln[4*t+2][0] + redln[4*t+3][0];
            float q4 = redln[4*t][1] + redln[4*t+1][1] + redln[4*t+2][1] + redln[4*t+3][1];
            float mu  = s4 * (1.f / 256.f);
            float var = q4 * (1.f / 256.f) - mu * mu;
            mu_s[t] = mu; rstd_s[t] = rsqrtf(var + 1e-5f);
        }
        __syncthreads();
        X[kq][c] = fmaxf((gv - mu_s[kq]) * rstd_s[kq] * g0[c] + be0[c], 0.f);
    }
    __syncthreads();

    float acc[4] = {0.f, 0.f, 0.f, 0.f};
    const float* Wp = W1 + h * 256 + c;
    const int kb0 = kq * 64;
    for (int kb = 0; kb < 64; kb += 16) {
        float wr[16];
#pragma unroll
        for (int u = 0; u < 16; ++u) wr[u] = Wp[(size_t)(kb0 + kb + u) * 1024];
#pragma unroll
        for (int u = 0; u < 16; ++u) {
            const int k = kb0 + kb + u;
            float w = wr[u];
            acc[0] += X[0][k] * w;
            acc[1] += X[1][k] * w;
            acc[2] += X[2][k] * w;
            acc[3] += X[3][k] * w;
        }
    }
    if (kq) {
#pragma unroll
        for (int n = 0; n < 4; ++n) xpart[kq - 1][n][c] = acc[n];
    }
    __syncthreads();

    if (kq == 0) {
#pragma unroll
        for (int n = 0; n < 4; ++n)
            acc[n] += xpart[0][n][c] + xpart[1][n][c] + xpart[2][n][c];

        const float av = as1[h * 256 + c], dv = ad1[h * 256 + c];
        float rv[8];
#pragma unroll
        for (int n = 0; n < 4; ++n) { rv[n] = acc[n] * av; rv[4 + n] = acc[n] * dv; }
#pragma unroll
        for (int i = 0; i < 8; ++i)
#pragma unroll
            for (int off = 32; off; off >>= 1)
                rv[i] += __shfl_down(rv[i], off, 64);
        if (lane == 0) {
#pragma unroll
            for (int i = 0; i < 8; ++i) redl[wv][i] = rv[i];
        }
    }
    __syncthreads();
    if (t < 8) esed[t] = redl[0][t] + redl[1][t] + redl[2][t] + redl[3][t];
    __syncthreads();

    if (t == 0) {   // only dst 0 (token) needed downstream
        const int srcs0[4] = {1, 2, 3, 0};
        float v[4], m = -1e30f;
        for (int s = 0; s < 4; ++s) {
            float e = esed[srcs0[s]] + esed[4];
            e = (e >= 0.f) ? e : 0.2f * e;
            v[s] = e; m = fmaxf(m, e);
        }
        float den = 0.f;
        for (int s = 0; s < 4; ++s) { v[s] = __expf(v[s] - m); den += v[s]; }
        float inv = 1.f / den;
        for (int s = 0; s < 4; ++s) alpha[0][s] = v[s] * inv;
    }
    __syncthreads();

    if (kq == 0) {
        const int srcs0[4] = {1, 2, 3, 0};
        float s = 0.f;
#pragma unroll
        for (int sl = 0; sl < 4; ++sl)
            s += alpha[0][sl] * acc[srcs0[sl]];
        msg2tok[(size_t)b * 1024 + h * 256 + c] = s;
    }
}

// ---------------- Kernel 2c: finish — token-row LN chain -> scale ----------------
__global__ __launch_bounds__(256) void finish_kernel(
    const float* __restrict__ tok,
    const float* __restrict__ msg1, const float* __restrict__ msg2tok,
    const float* __restrict__ b0, const float* __restrict__ g0,
    const float* __restrict__ be0,
    const float* __restrict__ b1, const float* __restrict__ g1,
    const float* __restrict__ be1,
    float* __restrict__ scale)
{
    const int b = blockIdx.x, c = threadIdx.x;
    const int lane = c & 63, wv = c >> 6;
    __shared__ float redl[4][2];
    __shared__ float mrs[2];

    const float* m1 = msg1 + (size_t)b * 4096 + c;
    float gv1 = 0.25f * (m1[0] + m1[1024] + m1[2048] + m1[3072]) + b0[c] + tok[c];
    {
        float s = gv1, q = gv1 * gv1;
#pragma unroll
        for (int off = 32; off; off >>= 1) { s += __shfl_down(s, off, 64); q += __shfl_down(q, off, 64); }
        if (lane == 0) { redl[wv][0] = s; redl[wv][1] = q; }
        __syncthreads();
        if (c == 0) {
            float ss = redl[0][0] + redl[1][0] + redl[2][0] + redl[3][0];
            float qq = redl[0][1] + redl[1][1] + redl[2][1] + redl[3][1];
            float mu = ss * (1.f / 256.f);
            mrs[0] = mu; mrs[1] = rsqrtf(qq * (1.f / 256.f) - mu * mu + 1e-5f);
        }
        __syncthreads();
    }
    float y1 = fmaxf((gv1 - mrs[0]) * mrs[1] * g0[c] + be0[c], 0.f);
    __syncthreads();

    const float* m2 = msg2tok + (size_t)b * 1024 + c;
    float gv2 = 0.25f * (m2[0] + m2[256] + m2[512] + m2[768]) + b1[c] + y1;
    {
        float s = gv2, q = gv2 * gv2;
#pragma unroll
        for (int off = 32; off; off >>= 1) { s += __shfl_down(s, off, 64); q += __shfl_down(q, off, 64); }
        if (lane == 0) { redl[wv][0] = s; redl[wv][1] = q; }
        __syncthreads();
        if (c == 0) {
            float ss = redl[0][0] + redl[1][0] + redl[2][0] + redl[3][0];
            float qq = redl[0][1] + redl[1][1] + redl[2][1] + redl[3][1];
            float mu = ss * (1.f / 256.f);
            mrs[0] = mu; mrs[1] = rsqrtf(qq * (1.f / 256.f) - mu * mu + 1e-5f);
        }
        __syncthreads();
    }
    float y2 = fmaxf((gv2 - mrs[0]) * mrs[1] * g1[c] + be1[c], 0.f);
    scale[(size_t)b * CCH + c] = 1.f + 1.f / (1.f + __expf(-y2));
}

// ---------------- Kernel 3: out = x_ful * (1 + sigmoid), nontemporal store ----------------
__global__ __launch_bounds__(256) void apply_kernel(
    const float* __restrict__ xf, const float* __restrict__ scale,
    float* __restrict__ out, int total4)
{
    int idx = blockIdx.x * 256 + threadIdx.x;
    const int stride = gridDim.x * 256;
    const f4* in4 = (const f4*)xf;
    f4* out4 = (f4*)out;
    for (; idx < total4; idx += stride) {
        f4 v = in4[idx];
        const float s = scale[idx >> 10];          // 1024 float4 per (b,c) row
        f4 o = v * s;
        __builtin_nontemporal_store(o, out4 + idx);
    }
}

extern "C" void kernel_launch(void* const* d_in, const int* in_sizes, int n_in,
                              void* d_out, int out_size, void* d_ws, size_t ws_size,
                              hipStream_t stream) {
    const float* x_ful = (const float*)d_in[0];
    const float* rgb   = (const float*)d_in[1];
    const float* dep   = (const float*)d_in[2];
    const float* tok   = (const float*)d_in[3];
    const float* W0  = (const float*)d_in[4];
    const float* as0 = (const float*)d_in[5];
    const float* ad0 = (const float*)d_in[6];
    const float* b0  = (const float*)d_in[7];
    const float* g0  = (const float*)d_in[8];
    const float* be0 = (const float*)d_in[9];
    const float* W1  = (const float*)d_in[10];
    const float* as1 = (const float*)d_in[11];
    const float* ad1 = (const float*)d_in[12];
    const float* b1  = (const float*)d_in[13];
    const float* g1  = (const float*)d_in[14];
    const float* be1 = (const float*)d_in[15];

    float* ws      = (float*)d_ws;
    float* nodes   = ws;                 // [32][4][256]    = 32768 floats
    float* scale   = ws + 32768;         // [32][256]       =  8192 floats
    float* msg1    = ws + 40960;         // [32][4][4][256] = 131072 floats
    float* msg2tok = ws + 172032;        // [32][4][256]    = 32768 floats
    float* out     = (float*)d_out;

    pool_kernel<<<24576, 256, 0, stream>>>(rgb, dep, x_ful, nodes);
    gatL0_kernel<<<128, 1024, 0, stream>>>(nodes, tok, W0, as0, ad0, msg1);
    gatL1_kernel<<<128, 1024, 0, stream>>>(nodes, tok, msg1, b0, g0, be0,
                                           W1, as1, ad1, msg2tok);
    finish_kernel<<<32, 256, 0, stream>>>(tok, msg1, msg2tok,
                                          b0, g0, be0, b1, g1, be1, scale);
    const int total4 = 32 * CCH * 64 * 64 / 4;            // 8,388,608 float4
    apply_kernel<<<2048, 256, 0, stream>>>(x_ful, scale, out, total4);
}

// Round 14
// 132.821 us; speedup vs baseline: 1.0311x; 1.0010x over previous
//
#include <hip/hip_runtime.h>
#include <hip/hip_bf16.h>

#define CCH 256

typedef float f4 __attribute__((ext_vector_type(4)));

__device__ __forceinline__ void load_lds16(const float* g, float* l) {
    __builtin_amdgcn_global_load_lds(
        (const __attribute__((address_space(1))) void*)g,
        (__attribute__((address_space(3))) void*)l, 16, 0, 0);
}

// ---------------- Kernel 1: pool via global_load_lds DMA ----------------
// Block per row (24576 blocks): 4 waves x 4 x global_load_lds(16B/lane) stage the
// 16 KB row into LDS with NO VGPR-return path -> 16 KB in flight per block,
// ~128 KB per CU (8 resident blocks), 8x the best VGPR-load variant (R11, 95us).
// Tests whether pool's 4.2 TB/s plateau is an outstanding-request limit (fix)
// or a hardware read ceiling (unchanged -> declare roofline).
__global__ __launch_bounds__(256) void pool_kernel(
    const float* __restrict__ rgb, const float* __restrict__ dep,
    const float* __restrict__ xf, float* __restrict__ nodes /* [32][4][256] */)
{
    const int bid = blockIdx.x;               // 0..24575
    const int t = threadIdx.x;                // 0..255
    const int lane = t & 63, wv = t >> 6;
    const int tensor = bid >> 13;             // 0 rgb, 1 dep, 2 x_ful
    const int row    = bid & 8191;            // b*256 + c
    const float* base = (tensor == 0) ? rgb : (tensor == 1) ? dep : xf;
    const float* src = base + (size_t)row * 4096;

    __shared__ __align__(16) float buf[4096]; // 16 KB row stage
    __shared__ float red[4];

    // wave wv stages floats [wv*1024, (wv+1)*1024): 4 issues of 1 KB each
#pragma unroll
    for (int j = 0; j < 4; ++j) {
        const int off = wv * 1024 + j * 256;      // floats; lane adds 4 floats (16B)
        load_lds16(src + off + lane * 4, buf + off);
    }
    __syncthreads();                              // drains vmcnt + barrier

    // conflict-free reduce: thread t sums buf[t + j*256] (stride-256 scalar reads,
    // lanes map to banks 0..31 twice -> 2-way aliasing = free)
    float s = 0.f;
#pragma unroll
    for (int j = 0; j < 16; ++j) s += buf[t + j * 256];
#pragma unroll
    for (int off = 32; off; off >>= 1) s += __shfl_down(s, off, 64);
    if (lane == 0) red[wv] = s;
    __syncthreads();
    if (t == 0) {
        const int b = row >> 8, c = row & 255;
        const int nrow = (tensor == 2) ? 1 : (2 + tensor);
        nodes[(size_t)b * 1024 + nrow * CCH + c] =
            (red[0] + red[1] + red[2] + red[3]) * (1.f / 4096.f);
    }
}

// ---------------- Kernel 2a: layer-0 per-(batch,head) GAT, K split across 4 groups ----------------
__global__ __launch_bounds__(1024) void gatL0_kernel(
    const float* __restrict__ nodes, const float* __restrict__ tok,
    const float* __restrict__ W0, const float* __restrict__ as0,
    const float* __restrict__ ad0, float* __restrict__ msg1)
{
    const int bid = blockIdx.x, b = bid >> 2, h = bid & 3;
    const int t = threadIdx.x, c = t & 255, kq = t >> 8;
    const int lane = t & 63, wv = t >> 6;       // wv 0..15

    __shared__ float X[4][CCH];
    __shared__ float xpart[3][4][CCH];          // kq=1..3 partials (12 KB)
    __shared__ float redl[4][8];
    __shared__ float esed[8];
    __shared__ float alpha[4][4];

    X[kq][c] = (kq == 0) ? tok[c] : nodes[(size_t)b * 1024 + kq * 256 + c];
    __syncthreads();

    float acc[4] = {0.f, 0.f, 0.f, 0.f};
    const float* Wp = W0 + h * 256 + c;
    const int kb0 = kq * 64;
    for (int kb = 0; kb < 64; kb += 16) {
        float wr[16];
#pragma unroll
        for (int u = 0; u < 16; ++u) wr[u] = Wp[(size_t)(kb0 + kb + u) * 1024];
#pragma unroll
        for (int u = 0; u < 16; ++u) {
            const int k = kb0 + kb + u;
            float w = wr[u];
            acc[0] += X[0][k] * w;
            acc[1] += X[1][k] * w;
            acc[2] += X[2][k] * w;
            acc[3] += X[3][k] * w;
        }
    }
    if (kq) {
#pragma unroll
        for (int n = 0; n < 4; ++n) xpart[kq - 1][n][c] = acc[n];
    }
    __syncthreads();

    if (kq == 0) {
#pragma unroll
        for (int n = 0; n < 4; ++n)
            acc[n] += xpart[0][n][c] + xpart[1][n][c] + xpart[2][n][c];

        const float av = as0[h * 256 + c], dv = ad0[h * 256 + c];
        float rv[8];
#pragma unroll
        for (int n = 0; n < 4; ++n) { rv[n] = acc[n] * av; rv[4 + n] = acc[n] * dv; }
#pragma unroll
        for (int i = 0; i < 8; ++i)
#pragma unroll
            for (int off = 32; off; off >>= 1)
                rv[i] += __shfl_down(rv[i], off, 64);
        if (lane == 0) {
#pragma unroll
            for (int i = 0; i < 8; ++i) redl[wv][i] = rv[i];
        }
    }
    __syncthreads();
    if (t < 8) esed[t] = redl[0][t] + redl[1][t] + redl[2][t] + redl[3][t];
    __syncthreads();

    if (t < 4) {
        const int cnt[4]     = {4, 3, 3, 3};
        const int srcs[4][4] = {{1,2,3,0},{2,3,1,0},{1,3,2,0},{1,2,3,0}};
        const int d = t, n = cnt[d];
        float v[4], m = -1e30f;
        for (int s = 0; s < n; ++s) {
            float e = esed[srcs[d][s]] + esed[4 + d];
            e = (e >= 0.f) ? e : 0.2f * e;           // leaky_relu 0.2
            v[s] = e; m = fmaxf(m, e);
        }
        float den = 0.f;
        for (int s = 0; s < n; ++s) { v[s] = __expf(v[s] - m); den += v[s]; }
        float inv = 1.f / den;
        for (int s = 0; s < n; ++s) alpha[d][s] = v[s] * inv;
        for (int s = n; s < 4; ++s) alpha[d][s] = 0.f;
    }
    __syncthreads();

    if (kq == 0) {
        const int srcs2[4][4] = {{1,2,3,0},{2,3,1,0},{1,3,2,0},{1,2,3,0}};
#pragma unroll
        for (int d = 0; d < 4; ++d) {
            float s = 0.f;
#pragma unroll
            for (int sl = 0; sl < 4; ++sl)
                s += alpha[d][sl] * acc[srcs2[d][sl]];
            msg1[(size_t)b * 4096 + h * 1024 + d * 256 + c] = s;
        }
    }
}

// ---------------- Kernel 2b: recompute gl1 + layer-1 GAT (token dst only) ----------------
__global__ __launch_bounds__(1024) void gatL1_kernel(
    const float* __restrict__ nodes, const float* __restrict__ tok,
    const float* __restrict__ msg1,
    const float* __restrict__ b0, const float* __restrict__ g0,
    const float* __restrict__ be0,
    const float* __restrict__ W1, const float* __restrict__ as1,
    const float* __restrict__ ad1, float* __restrict__ msg2tok)
{
    const int bid = blockIdx.x, b = bid >> 2, h = bid & 3;
    const int t = threadIdx.x, c = t & 255, kq = t >> 8;   // kq doubles as node d
    const int lane = t & 63, wv = t >> 6;

    __shared__ float X[4][CCH];                 // gl1
    __shared__ float xpart[3][4][CCH];
    __shared__ float redln[16][2];
    __shared__ float mu_s[4], rstd_s[4];
    __shared__ float redl[4][8];
    __shared__ float esed[8];
    __shared__ float alpha[4][4];

    {
        const float* m1 = msg1 + (size_t)b * 4096 + kq * 256 + c;  // h stride 1024
        float s = m1[0] + m1[1024] + m1[2048] + m1[3072];
        float x0 = (kq == 0) ? tok[c] : nodes[(size_t)b * 1024 + kq * 256 + c];
        float gv = 0.25f * s + b0[c] + x0;
        float ss = gv, qq = gv * gv;
#pragma unroll
        for (int off = 32; off; off >>= 1) {
            ss += __shfl_down(ss, off, 64);
            qq += __shfl_down(qq, off, 64);
        }
        if (lane == 0) { redln[wv][0] = ss; redln[wv][1] = qq; }
        __syncthreads();
        if (t < 4) {
            float s4 = redln[4*t][0] + redln[4*t+1][0] + redln[4*t+2][0] + redln[4*t+3][0];
            float q4 = redln[4*t][1] + redln[4*t+1][1] + redln[4*t+2][1] + redln[4*t+3][1];
            float mu  = s4 * (1.f / 256.f);
            float var = q4 * (1.f / 256.f) - mu * mu;
            mu_s[t] = mu; rstd_s[t] = rsqrtf(var + 1e-5f);
        }
        __syncthreads();
        X[kq][c] = fmaxf((gv - mu_s[kq]) * rstd_s[kq] * g0[c] + be0[c], 0.f);
    }
    __syncthreads();

    float acc[4] = {0.f, 0.f, 0.f, 0.f};
    const float* Wp = W1 + h * 256 + c;
    const int kb0 = kq * 64;
    for (int kb = 0; kb < 64; kb += 16) {
        float wr[16];
#pragma unroll
        for (int u = 0; u < 16; ++u) wr[u] = Wp[(size_t)(kb0 + kb + u) * 1024];
#pragma unroll
        for (int u = 0; u < 16; ++u) {
            const int k = kb0 + kb + u;
            float w = wr[u];
            acc[0] += X[0][k] * w;
            acc[1] += X[1][k] * w;
            acc[2] += X[2][k] * w;
            acc[3] += X[3][k] * w;
        }
    }
    if (kq) {
#pragma unroll
        for (int n = 0; n < 4; ++n) xpart[kq - 1][n][c] = acc[n];
    }
    __syncthreads();

    if (kq == 0) {
#pragma unroll
        for (int n = 0; n < 4; ++n)
            acc[n] += xpart[0][n][c] + xpart[1][n][c] + xpart[2][n][c];

        const float av = as1[h * 256 + c], dv = ad1[h * 256 + c];
        float rv[8];
#pragma unroll
        for (int n = 0; n < 4; ++n) { rv[n] = acc[n] * av; rv[4 + n] = acc[n] * dv; }
#pragma unroll
        for (int i = 0; i < 8; ++i)
#pragma unroll
            for (int off = 32; off; off >>= 1)
                rv[i] += __shfl_down(rv[i], off, 64);
        if (lane == 0) {
#pragma unroll
            for (int i = 0; i < 8; ++i) redl[wv][i] = rv[i];
        }
    }
    __syncthreads();
    if (t < 8) esed[t] = redl[0][t] + redl[1][t] + redl[2][t] + redl[3][t];
    __syncthreads();

    if (t == 0) {   // only dst 0 (token) needed downstream
        const int srcs0[4] = {1, 2, 3, 0};
        float v[4], m = -1e30f;
        for (int s = 0; s < 4; ++s) {
            float e = esed[srcs0[s]] + esed[4];
            e = (e >= 0.f) ? e : 0.2f * e;
            v[s] = e; m = fmaxf(m, e);
        }
        float den = 0.f;
        for (int s = 0; s < 4; ++s) { v[s] = __expf(v[s] - m); den += v[s]; }
        float inv = 1.f / den;
        for (int s = 0; s < 4; ++s) alpha[0][s] = v[s] * inv;
    }
    __syncthreads();

    if (kq == 0) {
        const int srcs0[4] = {1, 2, 3, 0};
        float s = 0.f;
#pragma unroll
        for (int sl = 0; sl < 4; ++sl)
            s += alpha[0][sl] * acc[srcs0[sl]];
        msg2tok[(size_t)b * 1024 + h * 256 + c] = s;
    }
}

// ---------------- Kernel 2c: finish — token-row LN chain -> scale ----------------
__global__ __launch_bounds__(256) void finish_kernel(
    const float* __restrict__ tok,
    const float* __restrict__ msg1, const float* __restrict__ msg2tok,
    const float* __restrict__ b0, const float* __restrict__ g0,
    const float* __restrict__ be0,
    const float* __restrict__ b1, const float* __restrict__ g1,
    const float* __restrict__ be1,
    float* __restrict__ scale)
{
    const int b = blockIdx.x, c = threadIdx.x;
    const int lane = c & 63, wv = c >> 6;
    __shared__ float redl[4][2];
    __shared__ float mrs[2];

    const float* m1 = msg1 + (size_t)b * 4096 + c;
    float gv1 = 0.25f * (m1[0] + m1[1024] + m1[2048] + m1[3072]) + b0[c] + tok[c];
    {
        float s = gv1, q = gv1 * gv1;
#pragma unroll
        for (int off = 32; off; off >>= 1) { s += __shfl_down(s, off, 64); q += __shfl_down(q, off, 64); }
        if (lane == 0) { redl[wv][0] = s; redl[wv][1] = q; }
        __syncthreads();
        if (c == 0) {
            float ss = redl[0][0] + redl[1][0] + redl[2][0] + redl[3][0];
            float qq = redl[0][1] + redl[1][1] + redl[2][1] + redl[3][1];
            float mu = ss * (1.f / 256.f);
            mrs[0] = mu; mrs[1] = rsqrtf(qq * (1.f / 256.f) - mu * mu + 1e-5f);
        }
        __syncthreads();
    }
    float y1 = fmaxf((gv1 - mrs[0]) * mrs[1] * g0[c] + be0[c], 0.f);
    __syncthreads();

    const float* m2 = msg2tok + (size_t)b * 1024 + c;
    float gv2 = 0.25f * (m2[0] + m2[256] + m2[512] + m2[768]) + b1[c] + y1;
    {
        float s = gv2, q = gv2 * gv2;
#pragma unroll
        for (int off = 32; off; off >>= 1) { s += __shfl_down(s, off, 64); q += __shfl_down(q, off, 64); }
        if (lane == 0) { redl[wv][0] = s; redl[wv][1] = q; }
        __syncthreads();
        if (c == 0) {
            float ss = redl[0][0] + redl[1][0] + redl[2][0] + redl[3][0];
            float qq = redl[0][1] + redl[1][1] + redl[2][1] + redl[3][1];
            float mu = ss * (1.f / 256.f);
            mrs[0] = mu; mrs[1] = rsqrtf(qq * (1.f / 256.f) - mu * mu + 1e-5f);
        }
        __syncthreads();
    }
    float y2 = fmaxf((gv2 - mrs[0]) * mrs[1] * g1[c] + be1[c], 0.f);
    scale[(size_t)b * CCH + c] = 1.f + 1.f / (1.f + __expf(-y2));
}

// ---------------- Kernel 3: out = x_ful * (1 + sigmoid), nontemporal store ----------------
__global__ __launch_bounds__(256) void apply_kernel(
    const float* __restrict__ xf, const float* __restrict__ scale,
    float* __restrict__ out, int total4)
{
    int idx = blockIdx.x * 256 + threadIdx.x;
    const int stride = gridDim.x * 256;
    const f4* in4 = (const f4*)xf;
    f4* out4 = (f4*)out;
    for (; idx < total4; idx += stride) {
        f4 v = in4[idx];
        const float s = scale[idx >> 10];          // 1024 float4 per (b,c) row
        f4 o = v * s;
        __builtin_nontemporal_store(o, out4 + idx);
    }
}

extern "C" void kernel_launch(void* const* d_in, const int* in_sizes, int n_in,
                              void* d_out, int out_size, void* d_ws, size_t ws_size,
                              hipStream_t stream) {
    const float* x_ful = (const float*)d_in[0];
    const float* rgb   = (const float*)d_in[1];
    const float* dep   = (const float*)d_in[2];
    const float* tok   = (const float*)d_in[3];
    const float* W0  = (const float*)d_in[4];
    const float* as0 = (const float*)d_in[5];
    const float* ad0 = (const float*)d_in[6];
    const float* b0  = (const float*)d_in[7];
    const float* g0  = (const float*)d_in[8];
    const float* be0 = (const float*)d_in[9];
    const float* W1  = (const float*)d_in[10];
    const float* as1 = (const float*)d_in[11];
    const float* ad1 = (const float*)d_in[12];
    const float* b1  = (const float*)d_in[13];
    const float* g1  = (const float*)d_in[14];
    const float* be1 = (const float*)d_in[15];

    float* ws      = (float*)d_ws;
    float* nodes   = ws;                 // [32][4][256]    = 32768 floats
    float* scale   = ws + 32768;         // [32][256]       =  8192 floats
    float* msg1    = ws + 40960;         // [32][4][4][256] = 131072 floats
    float* msg2tok = ws + 172032;        // [32][4][256]    = 32768 floats
    float* out     = (float*)d_out;

    pool_kernel<<<24576, 256, 0, stream>>>(rgb, dep, x_ful, nodes);
    gatL0_kernel<<<128, 1024, 0, stream>>>(nodes, tok, W0, as0, ad0, msg1);
    gatL1_kernel<<<128, 1024, 0, stream>>>(nodes, tok, msg1, b0, g0, be0,
                                           W1, as1, ad1, msg2tok);
    finish_kernel<<<32, 256, 0, stream>>>(tok, msg1, msg2tok,
                                          b0, g0, be0, b1, g1, be1, scale);
    const int total4 = 32 * CCH * 64 * 64 / 4;            // 8,388,608 float4
    apply_kernel<<<2048, 256, 0, stream>>>(x_ful, scale, out, total4);
}

// Round 15
// 126.445 us; speedup vs baseline: 1.0830x; 1.0504x over previous
//
#include <hip/hip_runtime.h>
#include <hip/hip_bf16.h>

#define CCH 256

typedef float f4 __attribute__((ext_vector_type(4)));

// ---------------- Kernel 1: merged pool (rgb, dep NT; x_ful temporal) ----------------
// EXACT R11 form — best of 7 measured variants (95 us; DMA/TLP/temporal all >=116).
// wave-per-row: 64 lanes x 16 f4, 16-deep burst, (256,2) bounds.
// rw: 0..8191 rgb -> row 2; 8192..16383 dep -> row 3; 16384..24575 x_ful -> row 1
// (x_ful last => freshest in L3 for apply).
__global__ __launch_bounds__(256, 2) void pool_kernel(
    const float* __restrict__ rgb, const float* __restrict__ dep,
    const float* __restrict__ xf, float* __restrict__ nodes /* [32][4][256] */)
{
    const int rw   = blockIdx.x * 4 + (threadIdx.x >> 6);  // 0..24575
    const int lane = threadIdx.x & 63;
    const int tensor = rw >> 13;              // 0 rgb, 1 dep, 2 x_ful
    const int row    = rw & 8191;             // b*256 + c
    const float* base = (tensor == 0) ? rgb : (tensor == 1) ? dep : xf;
    const f4* src = (const f4*)(base + (size_t)row * 4096);

    f4 acc;
    if (tensor < 2) {
        f4 v[16];
#pragma unroll
        for (int j = 0; j < 16; ++j) v[j] = __builtin_nontemporal_load(src + lane + 64 * j);
        f4 a0 = v[0] + v[1], a1 = v[2] + v[3], a2 = v[4] + v[5], a3 = v[6] + v[7];
        f4 a4 = v[8] + v[9], a5 = v[10] + v[11], a6 = v[12] + v[13], a7 = v[14] + v[15];
        acc = ((a0 + a1) + (a2 + a3)) + ((a4 + a5) + (a6 + a7));
    } else {
        f4 v[16];
#pragma unroll
        for (int j = 0; j < 16; ++j) v[j] = src[lane + 64 * j];
        f4 a0 = v[0] + v[1], a1 = v[2] + v[3], a2 = v[4] + v[5], a3 = v[6] + v[7];
        f4 a4 = v[8] + v[9], a5 = v[10] + v[11], a6 = v[12] + v[13], a7 = v[14] + v[15];
        acc = ((a0 + a1) + (a2 + a3)) + ((a4 + a5) + (a6 + a7));
    }

    float s = acc.x + acc.y + acc.z + acc.w;
#pragma unroll
    for (int off = 32; off; off >>= 1) s += __shfl_down(s, off, 64);
    if (lane == 0) {
        const int b = row >> 8, c = row & 255;
        const int nrow = (tensor == 2) ? 1 : (2 + tensor);
        nodes[(size_t)b * 1024 + nrow * CCH + c] = s * (1.f / 4096.f);
    }
}

// ---------------- Kernel 2a: layer-0 per-(batch,head) GAT, K split across 4 groups ----------------
__global__ __launch_bounds__(1024) void gatL0_kernel(
    const float* __restrict__ nodes, const float* __restrict__ tok,
    const float* __restrict__ W0, const float* __restrict__ as0,
    const float* __restrict__ ad0, float* __restrict__ msg1)
{
    const int bid = blockIdx.x, b = bid >> 2, h = bid & 3;
    const int t = threadIdx.x, c = t & 255, kq = t >> 8;
    const int lane = t & 63, wv = t >> 6;       // wv 0..15

    __shared__ float X[4][CCH];
    __shared__ float xpart[3][4][CCH];          // kq=1..3 partials (12 KB)
    __shared__ float redl[4][8];
    __shared__ float esed[8];
    __shared__ float alpha[4][4];

    X[kq][c] = (kq == 0) ? tok[c] : nodes[(size_t)b * 1024 + kq * 256 + c];
    __syncthreads();

    float acc[4] = {0.f, 0.f, 0.f, 0.f};
    const float* Wp = W0 + h * 256 + c;
    const int kb0 = kq * 64;
    for (int kb = 0; kb < 64; kb += 16) {
        float wr[16];
#pragma unroll
        for (int u = 0; u < 16; ++u) wr[u] = Wp[(size_t)(kb0 + kb + u) * 1024];
#pragma unroll
        for (int u = 0; u < 16; ++u) {
            const int k = kb0 + kb + u;
            float w = wr[u];
            acc[0] += X[0][k] * w;
            acc[1] += X[1][k] * w;
            acc[2] += X[2][k] * w;
            acc[3] += X[3][k] * w;
        }
    }
    if (kq) {
#pragma unroll
        for (int n = 0; n < 4; ++n) xpart[kq - 1][n][c] = acc[n];
    }
    __syncthreads();

    if (kq == 0) {
#pragma unroll
        for (int n = 0; n < 4; ++n)
            acc[n] += xpart[0][n][c] + xpart[1][n][c] + xpart[2][n][c];

        const float av = as0[h * 256 + c], dv = ad0[h * 256 + c];
        float rv[8];
#pragma unroll
        for (int n = 0; n < 4; ++n) { rv[n] = acc[n] * av; rv[4 + n] = acc[n] * dv; }
#pragma unroll
        for (int i = 0; i < 8; ++i)
#pragma unroll
            for (int off = 32; off; off >>= 1)
                rv[i] += __shfl_down(rv[i], off, 64);
        if (lane == 0) {
#pragma unroll
            for (int i = 0; i < 8; ++i) redl[wv][i] = rv[i];
        }
    }
    __syncthreads();
    if (t < 8) esed[t] = redl[0][t] + redl[1][t] + redl[2][t] + redl[3][t];
    __syncthreads();

    if (t < 4) {
        const int cnt[4]     = {4, 3, 3, 3};
        const int srcs[4][4] = {{1,2,3,0},{2,3,1,0},{1,3,2,0},{1,2,3,0}};
        const int d = t, n = cnt[d];
        float v[4], m = -1e30f;
        for (int s = 0; s < n; ++s) {
            float e = esed[srcs[d][s]] + esed[4 + d];
            e = (e >= 0.f) ? e : 0.2f * e;           // leaky_relu 0.2
            v[s] = e; m = fmaxf(m, e);
        }
        float den = 0.f;
        for (int s = 0; s < n; ++s) { v[s] = __expf(v[s] - m); den += v[s]; }
        float inv = 1.f / den;
        for (int s = 0; s < n; ++s) alpha[d][s] = v[s] * inv;
        for (int s = n; s < 4; ++s) alpha[d][s] = 0.f;
    }
    __syncthreads();

    if (kq == 0) {
        const int srcs2[4][4] = {{1,2,3,0},{2,3,1,0},{1,3,2,0},{1,2,3,0}};
#pragma unroll
        for (int d = 0; d < 4; ++d) {
            float s = 0.f;
#pragma unroll
            for (int sl = 0; sl < 4; ++sl)
                s += alpha[d][sl] * acc[srcs2[d][sl]];
            msg1[(size_t)b * 4096 + h * 1024 + d * 256 + c] = s;
        }
    }
}

// ---------------- Kernel 2b: recompute gl1 + layer-1 GAT (token dst only) ----------------
__global__ __launch_bounds__(1024) void gatL1_kernel(
    const float* __restrict__ nodes, const float* __restrict__ tok,
    const float* __restrict__ msg1,
    const float* __restrict__ b0, const float* __restrict__ g0,
    const float* __restrict__ be0,
    const float* __restrict__ W1, const float* __restrict__ as1,
    const float* __restrict__ ad1, float* __restrict__ msg2tok)
{
    const int bid = blockIdx.x, b = bid >> 2, h = bid & 3;
    const int t = threadIdx.x, c = t & 255, kq = t >> 8;   // kq doubles as node d
    const int lane = t & 63, wv = t >> 6;

    __shared__ float X[4][CCH];                 // gl1
    __shared__ float xpart[3][4][CCH];
    __shared__ float redln[16][2];
    __shared__ float mu_s[4], rstd_s[4];
    __shared__ float redl[4][8];
    __shared__ float esed[8];
    __shared__ float alpha[4][4];

    {
        const float* m1 = msg1 + (size_t)b * 4096 + kq * 256 + c;  // h stride 1024
        float s = m1[0] + m1[1024] + m1[2048] + m1[3072];
        float x0 = (kq == 0) ? tok[c] : nodes[(size_t)b * 1024 + kq * 256 + c];
        float gv = 0.25f * s + b0[c] + x0;
        float ss = gv, qq = gv * gv;
#pragma unroll
        for (int off = 32; off; off >>= 1) {
            ss += __shfl_down(ss, off, 64);
            qq += __shfl_down(qq, off, 64);
        }
        if (lane == 0) { redln[wv][0] = ss; redln[wv][1] = qq; }
        __syncthreads();
        if (t < 4) {
            float s4 = redln[4*t][0] + redln[4*t+1][0] + redln[4*t+2][0] + redln[4*t+3][0];
            float q4 = redln[4*t][1] + redln[4*t+1][1] + redln[4*t+2][1] + redln[4*t+3][1];
            float mu  = s4 * (1.f / 256.f);
            float var = q4 * (1.f / 256.f) - mu * mu;
            mu_s[t] = mu; rstd_s[t] = rsqrtf(var + 1e-5f);
        }
        __syncthreads();
        X[kq][c] = fmaxf((gv - mu_s[kq]) * rstd_s[kq] * g0[c] + be0[c], 0.f);
    }
    __syncthreads();

    float acc[4] = {0.f, 0.f, 0.f, 0.f};
    const float* Wp = W1 + h * 256 + c;
    const int kb0 = kq * 64;
    for (int kb = 0; kb < 64; kb += 16) {
        float wr[16];
#pragma unroll
        for (int u = 0; u < 16; ++u) wr[u] = Wp[(size_t)(kb0 + kb + u) * 1024];
#pragma unroll
        for (int u = 0; u < 16; ++u) {
            const int k = kb0 + kb + u;
            float w = wr[u];
            acc[0] += X[0][k] * w;
            acc[1] += X[1][k] * w;
            acc[2] += X[2][k] * w;
            acc[3] += X[3][k] * w;
        }
    }
    if (kq) {
#pragma unroll
        for (int n = 0; n < 4; ++n) xpart[kq - 1][n][c] = acc[n];
    }
    __syncthreads();

    if (kq == 0) {
#pragma unroll
        for (int n = 0; n < 4; ++n)
            acc[n] += xpart[0][n][c] + xpart[1][n][c] + xpart[2][n][c];

        const float av = as1[h * 256 + c], dv = ad1[h * 256 + c];
        float rv[8];
#pragma unroll
        for (int n = 0; n < 4; ++n) { rv[n] = acc[n] * av; rv[4 + n] = acc[n] * dv; }
#pragma unroll
        for (int i = 0; i < 8; ++i)
#pragma unroll
            for (int off = 32; off; off >>= 1)
                rv[i] += __shfl_down(rv[i], off, 64);
        if (lane == 0) {
#pragma unroll
            for (int i = 0; i < 8; ++i) redl[wv][i] = rv[i];
        }
    }
    __syncthreads();
    if (t < 8) esed[t] = redl[0][t] + redl[1][t] + redl[2][t] + redl[3][t];
    __syncthreads();

    if (t == 0) {   // only dst 0 (token) needed downstream
        const int srcs0[4] = {1, 2, 3, 0};
        float v[4], m = -1e30f;
        for (int s = 0; s < 4; ++s) {
            float e = esed[srcs0[s]] + esed[4];
            e = (e >= 0.f) ? e : 0.2f * e;
            v[s] = e; m = fmaxf(m, e);
        }
        float den = 0.f;
        for (int s = 0; s < 4; ++s) { v[s] = __expf(v[s] - m); den += v[s]; }
        float inv = 1.f / den;
        for (int s = 0; s < 4; ++s) alpha[0][s] = v[s] * inv;
    }
    __syncthreads();

    if (kq == 0) {
        const int srcs0[4] = {1, 2, 3, 0};
        float s = 0.f;
#pragma unroll
        for (int sl = 0; sl < 4; ++sl)
            s += alpha[0][sl] * acc[srcs0[sl]];
        msg2tok[(size_t)b * 1024 + h * 256 + c] = s;
    }
}

// ---------------- Kernel 2c: finish — token-row LN chain -> scale ----------------
__global__ __launch_bounds__(256) void finish_kernel(
    const float* __restrict__ tok,
    const float* __restrict__ msg1, const float* __restrict__ msg2tok,
    const float* __restrict__ b0, const float* __restrict__ g0,
    const float* __restrict__ be0,
    const float* __restrict__ b1, const float* __restrict__ g1,
    const float* __restrict__ be1,
    float* __restrict__ scale)
{
    const int b = blockIdx.x, c = threadIdx.x;
    const int lane = c & 63, wv = c >> 6;
    __shared__ float redl[4][2];
    __shared__ float mrs[2];

    const float* m1 = msg1 + (size_t)b * 4096 + c;
    float gv1 = 0.25f * (m1[0] + m1[1024] + m1[2048] + m1[3072]) + b0[c] + tok[c];
    {
        float s = gv1, q = gv1 * gv1;
#pragma unroll
        for (int off = 32; off; off >>= 1) { s += __shfl_down(s, off, 64); q += __shfl_down(q, off, 64); }
        if (lane == 0) { redl[wv][0] = s; redl[wv][1] = q; }
        __syncthreads();
        if (c == 0) {
            float ss = redl[0][0] + redl[1][0] + redl[2][0] + redl[3][0];
            float qq = redl[0][1] + redl[1][1] + redl[2][1] + redl[3][1];
            float mu = ss * (1.f / 256.f);
            mrs[0] = mu; mrs[1] = rsqrtf(qq * (1.f / 256.f) - mu * mu + 1e-5f);
        }
        __syncthreads();
    }
    float y1 = fmaxf((gv1 - mrs[0]) * mrs[1] * g0[c] + be0[c], 0.f);
    __syncthreads();

    const float* m2 = msg2tok + (size_t)b * 1024 + c;
    float gv2 = 0.25f * (m2[0] + m2[256] + m2[512] + m2[768]) + b1[c] + y1;
    {
        float s = gv2, q = gv2 * gv2;
#pragma unroll
        for (int off = 32; off; off >>= 1) { s += __shfl_down(s, off, 64); q += __shfl_down(q, off, 64); }
        if (lane == 0) { redl[wv][0] = s; redl[wv][1] = q; }
        __syncthreads();
        if (c == 0) {
            float ss = redl[0][0] + redl[1][0] + redl[2][0] + redl[3][0];
            float qq = redl[0][1] + redl[1][1] + redl[2][1] + redl[3][1];
            float mu = ss * (1.f / 256.f);
            mrs[0] = mu; mrs[1] = rsqrtf(qq * (1.f / 256.f) - mu * mu + 1e-5f);
        }
        __syncthreads();
    }
    float y2 = fmaxf((gv2 - mrs[0]) * mrs[1] * g1[c] + be1[c], 0.f);
    scale[(size_t)b * CCH + c] = 1.f + 1.f / (1.f + __expf(-y2));
}

// ---------------- Kernel 3: out = x_ful * (1 + sigmoid), nontemporal store ----------------
__global__ __launch_bounds__(256) void apply_kernel(
    const float* __restrict__ xf, const float* __restrict__ scale,
    float* __restrict__ out, int total4)
{
    int idx = blockIdx.x * 256 + threadIdx.x;
    const int stride = gridDim.x * 256;
    const f4* in4 = (const f4*)xf;
    f4* out4 = (f4*)out;
    for (; idx < total4; idx += stride) {
        f4 v = in4[idx];
        const float s = scale[idx >> 10];          // 1024 float4 per (b,c) row
        f4 o = v * s;
        __builtin_nontemporal_store(o, out4 + idx);
    }
}

extern "C" void kernel_launch(void* const* d_in, const int* in_sizes, int n_in,
                              void* d_out, int out_size, void* d_ws, size_t ws_size,
                              hipStream_t stream) {
    const float* x_ful = (const float*)d_in[0];
    const float* rgb   = (const float*)d_in[1];
    const float* dep   = (const float*)d_in[2];
    const float* tok   = (const float*)d_in[3];
    const float* W0  = (const float*)d_in[4];
    const float* as0 = (const float*)d_in[5];
    const float* ad0 = (const float*)d_in[6];
    const float* b0  = (const float*)d_in[7];
    const float* g0  = (const float*)d_in[8];
    const float* be0 = (const float*)d_in[9];
    const float* W1  = (const float*)d_in[10];
    const float* as1 = (const float*)d_in[11];
    const float* ad1 = (const float*)d_in[12];
    const float* b1  = (const float*)d_in[13];
    const float* g1  = (const float*)d_in[14];
    const float* be1 = (const float*)d_in[15];

    float* ws      = (float*)d_ws;
    float* nodes   = ws;                 // [32][4][256]    = 32768 floats
    float* scale   = ws + 32768;         // [32][256]       =  8192 floats
    float* msg1    = ws + 40960;         // [32][4][4][256] = 131072 floats
    float* msg2tok = ws + 172032;        // [32][4][256]    = 32768 floats
    float* out     = (float*)d_out;

    pool_kernel<<<6144, 256, 0, stream>>>(rgb, dep, x_ful, nodes);
    gatL0_kernel<<<128, 1024, 0, stream>>>(nodes, tok, W0, as0, ad0, msg1);
    gatL1_kernel<<<128, 1024, 0, stream>>>(nodes, tok, msg1, b0, g0, be0,
                                           W1, as1, ad1, msg2tok);
    finish_kernel<<<32, 256, 0, stream>>>(tok, msg1, msg2tok,
                                          b0, g0, be0, b1, g1, be1, scale);
    const int total4 = 32 * CCH * 64 * 64 / 4;            // 8,388,608 float4
    apply_kernel<<<2048, 256, 0, stream>>>(x_ful, scale, out, total4);
}